// Round 1
// baseline (754.203 us; speedup 1.0000x reference)
//
#include <hip/hip_runtime.h>
#include <stdint.h>

// Fused conv1(1->128) + relu + depthwise conv2 + relu + per-instrument FC + sigmoid.
// Roofline: wfc (426 MB fp32) must stream from HBM once per call -> ~68 us floor.
// Grid: 256 blocks = (instrument i) x (n-half of 44 cols). Block: 384 thr = 6 waves.
// K-loop: 50 slabs of 4 conv2 rows (K=192). Conv1 lives in registers with a rolling
// 2-row carry; conv2 writes bf16 A-tile to LDS; wfc is register-prefetched one slab
// ahead, cvt to bf16 B-tile. MFMA f32_16x16x32_bf16, 4 Mtiles x 3 Ntiles / 6 waves.

namespace {
constexpr int kB = 64, kI = 128, kN = 88, kT = 201, kF = 52;
constexpr int kT2 = 197, kF2 = 48;
constexpr int kFTOT = kT2 * kF2;  // 9456
constexpr int kNH = 44;           // n columns per block (88 / 2)
constexpr int kLDK = 200;         // LDS row stride in bf16: 192 + 8 pad (400 B; /16 odd)
constexpr int kSLABS = 50;        // 197 rows -> 49 slabs of 4 + 1 slab of 1
constexpr int kTHREADS = 384;

typedef float f32x4 __attribute__((ext_vector_type(4)));
typedef __bf16 bf16x8 __attribute__((ext_vector_type(8)));
typedef unsigned short u16x8 __attribute__((ext_vector_type(8)));
typedef unsigned short u16x4 __attribute__((ext_vector_type(4)));

__device__ __forceinline__ unsigned short bf16_rne(float f) {
  unsigned int u = __float_as_uint(f);
  u += 0x7fffu + ((u >> 16) & 1u);  // round-to-nearest-even
  return (unsigned short)(u >> 16);
}

__device__ __forceinline__ void loadrow(float* d, const float* p) {
  float4 a = *(const float4*)p;
  float4 b = *(const float4*)(p + 4);
  float4 c = *(const float4*)(p + 8);
  d[0] = a.x; d[1] = a.y; d[2] = a.z;  d[3] = a.w;
  d[4] = b.x; d[5] = b.y; d[6] = b.z;  d[7] = b.w;
  d[8] = c.x; d[9] = c.y; d[10] = c.z; d[11] = c.w;
}

__device__ __forceinline__ void c1row(float* o, const float* r0, const float* r1,
                                      const float* r2, const float* w, float bias) {
#pragma unroll
  for (int c = 0; c < 10; ++c) {
    float v = bias;
    v += r0[c] * w[0]; v += r0[c + 1] * w[1]; v += r0[c + 2] * w[2];
    v += r1[c] * w[3]; v += r1[c + 1] * w[4]; v += r1[c + 2] * w[5];
    v += r2[c] * w[6]; v += r2[c + 1] * w[7]; v += r2[c + 2] * w[8];
    o[c] = fmaxf(v, 0.0f);
  }
}
}  // namespace

__global__ __launch_bounds__(kTHREADS, 2) void fused_conv_fc_kernel(
    const float* __restrict__ data, const float* __restrict__ w1,
    const float* __restrict__ b1, const float* __restrict__ w2,
    const float* __restrict__ b2, const float* __restrict__ wfc,
    const float* __restrict__ bfc, float* __restrict__ out) {
  __shared__ unsigned short Ab[kB * kLDK];  // 25600 B : A-tile  [batch][k]
  __shared__ unsigned short Bb[48 * kLDK];  // 19200 B : B-tile  [n][k]

  const int tid = threadIdx.x;
  const int i = blockIdx.x >> 1;
  const int nh = blockIdx.x & 1;
  const int nbase = nh * kNH;

  // zero B pad rows [44,48) once (LDS is poisoned 0xAA by harness)
  for (int z = tid; z < 4 * kLDK; z += kTHREADS) Bb[kNH * kLDK + z] = 0;

  // per-instrument conv weights (block-uniform -> SGPRs)
  float w1r[9], w2r[9];
#pragma unroll
  for (int j = 0; j < 9; ++j) { w1r[j] = w1[i * 9 + j]; w2r[j] = w2[i * 9 + j]; }
  const float b1r = b1[i], b2r = b2[i];

  // conv thread mapping: (batch, 8-wide col strip)
  const int bb = tid / 6;
  const int oc = tid - bb * 6;
  const int fr0 = oc * 8;  // conv2 col base; conv1 cols fr0..fr0+9; data cols fr0..fr0+11
  const float* dbase = data + bb * (kT * kF) + fr0;

  float c1[6][10];                     // conv1 rows 4s..4s+5 (post-relu)
  float dA[12], dB[12], dC[12], dD[12];  // rolling data rows
  float4 W[6];                         // wfc prefetch (next slab)

  // ---- prologue: conv1 rows 0,1; leave dA=data row2, dB=row3 ----
  loadrow(dC, dbase + 0 * kF);
  loadrow(dD, dbase + 1 * kF);
  loadrow(dA, dbase + 2 * kF);
  loadrow(dB, dbase + 3 * kF);
  c1row(c1[0], dC, dD, dA, w1r, b1r);
  c1row(c1[1], dD, dA, dB, w1r, b1r);

  // ---- prologue: wfc prefetch for slab 0 ----
#pragma unroll
  for (int j = 0; j < 6; ++j) {
    int q = tid + kTHREADS * j;
    if (q < kNH * 48) {
      int n = q / 48, k4 = q - n * 48;
      W[j] = *(const float4*)(wfc + (size_t)(i * kN + nbase + n) * kFTOT + k4 * 4);
    } else {
      W[j] = make_float4(0.f, 0.f, 0.f, 0.f);
    }
  }

  // MFMA assignment: wave wv -> (Ntile nt, Mtile pair mp)
  const int wv = tid >> 6, ln = tid & 63;
  const int nt = wv % 3, mp = wv / 3;
  const int lc = ln & 15, lq = ln >> 4;
  f32x4 acc0 = {0.f, 0.f, 0.f, 0.f};
  f32x4 acc1 = {0.f, 0.f, 0.f, 0.f};

  for (int s = 0; s < kSLABS; ++s) {
    // ---- conv1 rows 4s+2..4s+5 in registers (rolling data rows) ----
    loadrow(dC, dbase + (4 * s + 4) * kF);
    c1row(c1[2], dA, dB, dC, w1r, b1r);
    if (s < kSLABS - 1) {
      loadrow(dD, dbase + (4 * s + 5) * kF);
      c1row(c1[3], dB, dC, dD, w1r, b1r);
      loadrow(dA, dbase + (4 * s + 6) * kF);
      c1row(c1[4], dC, dD, dA, w1r, b1r);
      loadrow(dB, dbase + (4 * s + 7) * kF);
      c1row(c1[5], dD, dA, dB, w1r, b1r);
      // rotation leaves dA=row 4(s+1)+2, dB=row 4(s+1)+3 automatically
    }
    // ---- conv2 + relu -> bf16 A-tile (k = tl*48 + fr0 + c) ----
#pragma unroll
    for (int tl = 0; tl < 4; ++tl) {
      if (tl == 0 || s < kSLABS - 1) {  // last slab has 1 valid row (t2=196)
        u16x8 o8;
#pragma unroll
        for (int c = 0; c < 8; ++c) {
          float v = b2r;
#pragma unroll
          for (int r = 0; r < 3; ++r) {
            v += c1[tl + r][c] * w2r[3 * r];
            v += c1[tl + r][c + 1] * w2r[3 * r + 1];
            v += c1[tl + r][c + 2] * w2r[3 * r + 2];
          }
          o8[c] = bf16_rne(fmaxf(v, 0.0f));
        }
        *(u16x8*)&Ab[bb * kLDK + tl * 48 + fr0] = o8;  // 16B aligned ds_write_b128
      }
    }
    // ---- stage B-tile from prefetched W (fp32 -> bf16) ----
#pragma unroll
    for (int j = 0; j < 6; ++j) {
      int q = tid + kTHREADS * j;
      if (q < kNH * 48) {
        int n = q / 48, k4 = q - n * 48;
        u16x4 o;
        o[0] = bf16_rne(W[j].x); o[1] = bf16_rne(W[j].y);
        o[2] = bf16_rne(W[j].z); o[3] = bf16_rne(W[j].w);
        *(u16x4*)&Bb[n * kLDK + k4 * 4] = o;
      }
    }
    // ---- prefetch next slab's wfc (in flight across MFMA + next conv) ----
    if (s + 1 < kSLABS) {
      const int real4 = (s + 1 == kSLABS - 1) ? 12 : 48;  // last slab: 48 real k, pad 0
#pragma unroll
      for (int j = 0; j < 6; ++j) {
        int q = tid + kTHREADS * j;
        int n = q / 48, k4 = q - n * 48;
        if (q < kNH * 48 && k4 < real4) {
          W[j] = *(const float4*)(wfc + (size_t)(i * kN + nbase + n) * kFTOT +
                                  (size_t)(s + 1) * 192 + k4 * 4);
        } else {
          W[j] = make_float4(0.f, 0.f, 0.f, 0.f);
        }
      }
    }
    __syncthreads();
    // ---- MFMA: 2 tiles/wave, K=192 (last slab K=64 incl. zero pad) ----
    {
      const unsigned short* Ar0 = &Ab[(mp * 32 + lc) * kLDK];
      const unsigned short* Ar1 = Ar0 + 16 * kLDK;
      const unsigned short* Br = &Bb[(nt * 16 + lc) * kLDK];
      const int kq = lq * 8;
      if (s != kSLABS - 1) {
#pragma unroll
        for (int ks = 0; ks < 6; ++ks) {
          int ko = ks * 32 + kq;
          bf16x8 a0 = *(const bf16x8*)(Ar0 + ko);
          bf16x8 a1 = *(const bf16x8*)(Ar1 + ko);
          bf16x8 bfr = *(const bf16x8*)(Br + ko);
          acc0 = __builtin_amdgcn_mfma_f32_16x16x32_bf16(a0, bfr, acc0, 0, 0, 0);
          acc1 = __builtin_amdgcn_mfma_f32_16x16x32_bf16(a1, bfr, acc1, 0, 0, 0);
        }
      } else {
#pragma unroll
        for (int ks = 0; ks < 2; ++ks) {
          int ko = ks * 32 + kq;
          bf16x8 a0 = *(const bf16x8*)(Ar0 + ko);
          bf16x8 a1 = *(const bf16x8*)(Ar1 + ko);
          bf16x8 bfr = *(const bf16x8*)(Br + ko);
          acc0 = __builtin_amdgcn_mfma_f32_16x16x32_bf16(a0, bfr, acc0, 0, 0, 0);
          acc1 = __builtin_amdgcn_mfma_f32_16x16x32_bf16(a1, bfr, acc1, 0, 0, 0);
        }
      }
    }
    __syncthreads();
    // ---- carry conv1 rows 4s+4,4s+5 -> rows 4(s+1),4(s+1)+1 ----
    if (s < kSLABS - 1) {
#pragma unroll
      for (int c = 0; c < 10; ++c) { c1[0][c] = c1[4][c]; c1[1][c] = c1[5][c]; }
    }
  }

  // ---- epilogue: C layout col=lane&15, row=(lane>>4)*4+reg; +bfc, sigmoid ----
  const int nl = nt * 16 + lc;
  if (nl < kNH) {
    const int ng = nbase + nl;
    const float bias = bfc[i * kN + ng];
#pragma unroll
    for (int r = 0; r < 4; ++r) {
      int b0 = mp * 32 + lq * 4 + r;
      float v0 = acc0[r] + bias;
      out[(size_t)(b0 * kI + i) * kN + ng] = 1.0f / (1.0f + __expf(-v0));
      float v1 = acc1[r] + bias;
      out[(size_t)((b0 + 16) * kI + i) * kN + ng] = 1.0f / (1.0f + __expf(-v1));
    }
  }
}

extern "C" void kernel_launch(void* const* d_in, const int* in_sizes, int n_in,
                              void* d_out, int out_size, void* d_ws, size_t ws_size,
                              hipStream_t stream) {
  const float* data = (const float*)d_in[0];
  const float* w1 = (const float*)d_in[1];
  const float* b1 = (const float*)d_in[2];
  const float* w2 = (const float*)d_in[3];
  const float* b2 = (const float*)d_in[4];
  const float* wfc = (const float*)d_in[5];
  const float* bfc = (const float*)d_in[6];
  float* out = (float*)d_out;
  fused_conv_fc_kernel<<<dim3(kI * 2), dim3(kTHREADS), 0, stream>>>(
      data, w1, b1, w2, b2, wfc, bfc, out);
}

// Round 2
// 705.131 us; speedup vs baseline: 1.0696x; 1.0696x over previous
//
#include <hip/hip_runtime.h>
#include <stdint.h>

// Two-kernel split:
//  K1 conv_kernel: conv1(1->128)+relu+depthwise conv2+relu -> x bf16 [B][I][9456] in d_ws.
//     Grid 512 = 128 i x 4 row-groups, 384 thr, register-rolling conv, no LDS.
//  K2 gemm_kernel: out[b,i,n] = sigmoid(x[b,i,:].wfc[i,n,:]+bfc). Grid 256 = i x nhalf.
//     K-slab 128, LDS double-buffered A+B, ONE lgkm-only barrier per slab (no vmcnt
//     drain -> global loads stay in flight across barriers), tiles register-prefetched
//     one full slab ahead with two alternating register sets.
// Fallback: round-1 fused kernel if ws_size too small.

namespace {
constexpr int kB = 64, kI = 128, kN = 88, kT = 201, kF = 52;
constexpr int kT2 = 197, kF2 = 48;
constexpr int kFTOT = kT2 * kF2;  // 9456
constexpr int kNH = 44;
constexpr int kTHREADS = 384;
// K2
constexpr int kKS = 128;  // slab K
constexpr int kNS = 74;   // 73*128 + 112 = 9456
constexpr int kLDB = 152; // B row stride in bf16 (304 B = 19*16 -> spread banks)
// fallback fused kernel
constexpr int kLDK = 200;
constexpr int kSLABS = 50;

typedef float f32x4 __attribute__((ext_vector_type(4)));
typedef __bf16 bf16x8 __attribute__((ext_vector_type(8)));
typedef unsigned short u16x8 __attribute__((ext_vector_type(8)));
typedef unsigned short u16x4 __attribute__((ext_vector_type(4)));

#define BAR_LGKM() asm volatile("s_waitcnt lgkmcnt(0)\n\ts_barrier" ::: "memory")

__device__ __forceinline__ unsigned short bf16_rne(float f) {
  unsigned int u = __float_as_uint(f);
  u += 0x7fffu + ((u >> 16) & 1u);
  return (unsigned short)(u >> 16);
}

__device__ __forceinline__ void loadrow(float* d, const float* p) {
  float4 a = *(const float4*)p;
  float4 b = *(const float4*)(p + 4);
  float4 c = *(const float4*)(p + 8);
  d[0] = a.x; d[1] = a.y; d[2] = a.z;  d[3] = a.w;
  d[4] = b.x; d[5] = b.y; d[6] = b.z;  d[7] = b.w;
  d[8] = c.x; d[9] = c.y; d[10] = c.z; d[11] = c.w;
}

__device__ __forceinline__ void c1row(float* o, const float* r0, const float* r1,
                                      const float* r2, const float* w, float bias) {
#pragma unroll
  for (int c = 0; c < 10; ++c) {
    float v = bias;
    v += r0[c] * w[0]; v += r0[c + 1] * w[1]; v += r0[c + 2] * w[2];
    v += r1[c] * w[3]; v += r1[c + 1] * w[4]; v += r1[c + 2] * w[5];
    v += r2[c] * w[6]; v += r2[c + 1] * w[7]; v += r2[c + 2] * w[8];
    o[c] = fmaxf(v, 0.0f);
  }
}
}  // namespace

// ---------------------------------------------------------------- K1: conv
namespace {
__device__ __forceinline__ void conv_step(const float* dbase, int lrow,
    float* dNew, const float* dP2, const float* dP1,
    float* c1n, const float* c1x, const float* c1y,
    unsigned short* xout, int t2,
    const float* w1r, float b1r, const float* w2r, float b2r) {
  loadrow(dNew, dbase + lrow * kF);
  c1row(c1n, dP2, dP1, dNew, w1r, b1r);
  u16x8 o8;
#pragma unroll
  for (int c = 0; c < 8; ++c) {
    float v = b2r;
    v += c1x[c] * w2r[0] + c1x[c + 1] * w2r[1] + c1x[c + 2] * w2r[2];
    v += c1y[c] * w2r[3] + c1y[c + 1] * w2r[4] + c1y[c + 2] * w2r[5];
    v += c1n[c] * w2r[6] + c1n[c + 1] * w2r[7] + c1n[c + 2] * w2r[8];
    o8[c] = bf16_rne(fmaxf(v, 0.0f));
  }
  *(u16x8*)(xout + (size_t)t2 * kF2) = o8;
}
}  // namespace

__global__ __launch_bounds__(kTHREADS, 3) void conv_kernel(
    const float* __restrict__ data, const float* __restrict__ w1,
    const float* __restrict__ b1, const float* __restrict__ w2,
    const float* __restrict__ b2, unsigned short* __restrict__ x) {
  const int i = blockIdx.x >> 2, rg = blockIdx.x & 3;
  const int base = rg * 50;
  const int ntrip = (rg == 3) ? 15 : 16;  // 3*ntrip + 2 rows per group (50/50/50/47)
  const int tid = threadIdx.x;
  const int bb = tid / 6, oc = tid - bb * 6;
  const float* dbase = data + bb * (kT * kF) + oc * 8;
  unsigned short* xout = x + ((size_t)(bb * kI + i)) * kFTOT + oc * 8;

  float w1r[9], w2r[9];
#pragma unroll
  for (int j = 0; j < 9; ++j) { w1r[j] = w1[i * 9 + j]; w2r[j] = w2[i * 9 + j]; }
  const float b1r = b1[i], b2r = b2[i];

  float dA[12], dB[12], dC[12], c1A[10], c1B[10], c1C[10];
  // prologue: end state dA=row base+2, dB=row base+3, c1A=c1[base], c1B=c1[base+1]
  loadrow(dB, dbase + (base + 0) * kF);
  loadrow(dC, dbase + (base + 1) * kF);
  loadrow(dA, dbase + (base + 2) * kF);
  c1row(c1A, dB, dC, dA, w1r, b1r);
  loadrow(dB, dbase + (base + 3) * kF);
  c1row(c1B, dC, dA, dB, w1r, b1r);

  int t2 = base;
  for (int tt = 0; tt < ntrip; ++tt, t2 += 3) {
    conv_step(dbase, t2 + 4, dC, dA, dB, c1C, c1A, c1B, xout, t2, w1r, b1r, w2r, b2r);
    conv_step(dbase, t2 + 5, dA, dB, dC, c1A, c1B, c1C, xout, t2 + 1, w1r, b1r, w2r, b2r);
    conv_step(dbase, t2 + 6, dB, dC, dA, c1B, c1C, c1A, xout, t2 + 2, w1r, b1r, w2r, b2r);
  }
  // 2 remainder rows
  conv_step(dbase, t2 + 4, dC, dA, dB, c1C, c1A, c1B, xout, t2, w1r, b1r, w2r, b2r);
  conv_step(dbase, t2 + 5, dA, dB, dC, c1A, c1B, c1C, xout, t2 + 1, w1r, b1r, w2r, b2r);
}

// ---------------------------------------------------------------- K2: gemm
namespace {
struct Regs {
  u16x8 a[3];
  float4 w[4];
};

__device__ __forceinline__ void issue_tiles(Regs& R, const unsigned short* x,
                                            const float* wfc, int i, int nbase,
                                            int t, int tid) {
  // A: 1024 chunks of 8 bf16; q -> b = q>>4, c = q&15 (c fastest: 256 B runs)
#pragma unroll
  for (int j = 0; j < 3; ++j) {
    int q = tid + kTHREADS * j;
    if (q < 1024) {
      int b = q >> 4, c = q & 15;
      int k0 = t * kKS + c * 8;
      if (k0 < kFTOT) {
        R.a[j] = *(const u16x8*)(x + ((size_t)(b * kI + i)) * kFTOT + k0);
      } else {
        u16x8 z = {0, 0, 0, 0, 0, 0, 0, 0};
        R.a[j] = z;
      }
    }
  }
  // B: 44 n x 32 float4; q -> n = q>>5, k4 = q&31 (512 B runs per n)
#pragma unroll
  for (int j = 0; j < 4; ++j) {
    int q = tid + kTHREADS * j;
    if (q < kNH * 32) {
      int n = q >> 5, k4 = q & 31;
      int k0 = t * kKS + k4 * 4;
      if (k0 < kFTOT) {
        R.w[j] = *(const float4*)(wfc + ((size_t)(i * kN + nbase + n)) * kFTOT + k0);
      } else {
        R.w[j] = make_float4(0.f, 0.f, 0.f, 0.f);
      }
    }
  }
}

__device__ __forceinline__ void stage_tiles(const Regs& R, unsigned short* Abuf,
                                            unsigned short* Bbuf, int tid) {
#pragma unroll
  for (int j = 0; j < 3; ++j) {
    int q = tid + kTHREADS * j;
    if (q < 1024) {
      int b = q >> 4, c = q & 15;
      int slot = c * 64 + ((b + c) & 63);  // bank-rotating swizzle
      *(u16x8*)(Abuf + slot * 8) = R.a[j];
    }
  }
#pragma unroll
  for (int j = 0; j < 4; ++j) {
    int q = tid + kTHREADS * j;
    if (q < kNH * 32) {
      int n = q >> 5, k4 = q & 31;
      u16x4 o;
      o[0] = bf16_rne(R.w[j].x); o[1] = bf16_rne(R.w[j].y);
      o[2] = bf16_rne(R.w[j].z); o[3] = bf16_rne(R.w[j].w);
      *(u16x4*)(Bbuf + n * kLDB + k4 * 4) = o;
    }
  }
}
}  // namespace

__global__ __launch_bounds__(kTHREADS, 2) void gemm_kernel(
    const unsigned short* __restrict__ x, const float* __restrict__ wfc,
    const float* __restrict__ bfc, float* __restrict__ out) {
  __shared__ unsigned short A[2][1024 * 8];   // 2 x 16 KB
  __shared__ unsigned short Bt[2][48 * kLDB]; // 2 x 14.25 KB
  const int tid = threadIdx.x;
  const int i = blockIdx.x >> 1, nh = blockIdx.x & 1, nbase = nh * kNH;

  // zero B pad rows [44,48) in both buffers (written never after)
  for (int z = tid; z < 4 * kLDB; z += kTHREADS) {
    Bt[0][kNH * kLDB + z] = 0;
    Bt[1][kNH * kLDB + z] = 0;
  }

  Regs R0, R1;  // R0 holds even tiles, R1 odd tiles
  issue_tiles(R0, x, wfc, i, nbase, 0, tid);
  stage_tiles(R0, A[0], Bt[0], tid);  // waits R0 loads
  issue_tiles(R1, x, wfc, i, nbase, 1, tid);

  const int wv = tid >> 6, ln = tid & 63;
  const int nt = wv % 3, mp = wv / 3;
  const int lc = ln & 15, lq = ln >> 4;
  f32x4 acc0 = {0.f, 0.f, 0.f, 0.f};
  f32x4 acc1 = {0.f, 0.f, 0.f, 0.f};

  BAR_LGKM();

  auto body = [&](int s, Regs& Rst, Regs& Ris) {
    const int p = s & 1;
    if (s + 1 < kNS) stage_tiles(Rst, A[1 - p], Bt[1 - p], tid);  // waits Rst loads
    if (s + 2 < kNS) issue_tiles(Ris, x, wfc, i, nbase, s + 2, tid);
    const unsigned short* Ap = A[p];
    const unsigned short* Bp = &Bt[p][(nt * 16 + lc) * kLDB + lq * 8];
    const int m0 = mp * 32 + lc;
#pragma unroll
    for (int ks = 0; ks < 4; ++ks) {
      const int c = ks * 4 + lq;
      bf16x8 a0 = *(const bf16x8*)(Ap + (c * 64 + ((m0 + c) & 63)) * 8);
      bf16x8 a1 = *(const bf16x8*)(Ap + (c * 64 + ((m0 + 16 + c) & 63)) * 8);
      bf16x8 bb = *(const bf16x8*)(Bp + ks * 32);
      acc0 = __builtin_amdgcn_mfma_f32_16x16x32_bf16(a0, bb, acc0, 0, 0, 0);
      acc1 = __builtin_amdgcn_mfma_f32_16x16x32_bf16(a1, bb, acc1, 0, 0, 0);
    }
    BAR_LGKM();  // lgkm-only: global prefetch loads stay in flight
  };

  for (int s = 0; s < kNS; s += 2) {
    body(s, R1, R0);      // stage odd tile s+1 from R1, refill R0 with tile s+2
    body(s + 1, R0, R1);  // stage even tile s+2 from R0, refill R1 with tile s+3
  }

  // epilogue: C layout col=lane&15, row=(lane>>4)*4+reg; +bfc, sigmoid
  const int nl = nt * 16 + lc;
  if (nl < kNH) {
    const int ng = nbase + nl;
    const float bias = bfc[i * kN + ng];
#pragma unroll
    for (int r = 0; r < 4; ++r) {
      int b0 = mp * 32 + lq * 4 + r;
      float v0 = acc0[r] + bias;
      out[(size_t)(b0 * kI + i) * kN + ng] = 1.0f / (1.0f + __expf(-v0));
      float v1 = acc1[r] + bias;
      out[(size_t)((b0 + 16) * kI + i) * kN + ng] = 1.0f / (1.0f + __expf(-v1));
    }
  }
}

// ------------------------------------------------- fallback: round-1 fused
__global__ __launch_bounds__(kTHREADS, 2) void fused_conv_fc_kernel(
    const float* __restrict__ data, const float* __restrict__ w1,
    const float* __restrict__ b1, const float* __restrict__ w2,
    const float* __restrict__ b2, const float* __restrict__ wfc,
    const float* __restrict__ bfc, float* __restrict__ out) {
  __shared__ unsigned short Ab[kB * kLDK];
  __shared__ unsigned short Bb[48 * kLDK];
  const int tid = threadIdx.x;
  const int i = blockIdx.x >> 1;
  const int nh = blockIdx.x & 1;
  const int nbase = nh * kNH;
  for (int z = tid; z < 4 * kLDK; z += kTHREADS) Bb[kNH * kLDK + z] = 0;
  float w1r[9], w2r[9];
#pragma unroll
  for (int j = 0; j < 9; ++j) { w1r[j] = w1[i * 9 + j]; w2r[j] = w2[i * 9 + j]; }
  const float b1r = b1[i], b2r = b2[i];
  const int bb = tid / 6;
  const int oc = tid - bb * 6;
  const int fr0 = oc * 8;
  const float* dbase = data + bb * (kT * kF) + fr0;
  float c1[6][10];
  float dA[12], dB[12], dC[12], dD[12];
  float4 W[6];
  loadrow(dC, dbase + 0 * kF);
  loadrow(dD, dbase + 1 * kF);
  loadrow(dA, dbase + 2 * kF);
  loadrow(dB, dbase + 3 * kF);
  c1row(c1[0], dC, dD, dA, w1r, b1r);
  c1row(c1[1], dD, dA, dB, w1r, b1r);
#pragma unroll
  for (int j = 0; j < 6; ++j) {
    int q = tid + kTHREADS * j;
    if (q < kNH * 48) {
      int n = q / 48, k4 = q - n * 48;
      W[j] = *(const float4*)(wfc + (size_t)(i * kN + nbase + n) * kFTOT + k4 * 4);
    } else {
      W[j] = make_float4(0.f, 0.f, 0.f, 0.f);
    }
  }
  const int wv = tid >> 6, ln = tid & 63;
  const int nt = wv % 3, mp = wv / 3;
  const int lc = ln & 15, lq = ln >> 4;
  f32x4 acc0 = {0.f, 0.f, 0.f, 0.f};
  f32x4 acc1 = {0.f, 0.f, 0.f, 0.f};
  for (int s = 0; s < kSLABS; ++s) {
    loadrow(dC, dbase + (4 * s + 4) * kF);
    c1row(c1[2], dA, dB, dC, w1r, b1r);
    if (s < kSLABS - 1) {
      loadrow(dD, dbase + (4 * s + 5) * kF);
      c1row(c1[3], dB, dC, dD, w1r, b1r);
      loadrow(dA, dbase + (4 * s + 6) * kF);
      c1row(c1[4], dC, dD, dA, w1r, b1r);
      loadrow(dB, dbase + (4 * s + 7) * kF);
      c1row(c1[5], dD, dA, dB, w1r, b1r);
    }
#pragma unroll
    for (int tl = 0; tl < 4; ++tl) {
      if (tl == 0 || s < kSLABS - 1) {
        u16x8 o8;
#pragma unroll
        for (int c = 0; c < 8; ++c) {
          float v = b2r;
#pragma unroll
          for (int r = 0; r < 3; ++r) {
            v += c1[tl + r][c] * w2r[3 * r];
            v += c1[tl + r][c + 1] * w2r[3 * r + 1];
            v += c1[tl + r][c + 2] * w2r[3 * r + 2];
          }
          o8[c] = bf16_rne(fmaxf(v, 0.0f));
        }
        *(u16x8*)&Ab[bb * kLDK + tl * 48 + fr0] = o8;
      }
    }
#pragma unroll
    for (int j = 0; j < 6; ++j) {
      int q = tid + kTHREADS * j;
      if (q < kNH * 48) {
        int n = q / 48, k4 = q - n * 48;
        u16x4 o;
        o[0] = bf16_rne(W[j].x); o[1] = bf16_rne(W[j].y);
        o[2] = bf16_rne(W[j].z); o[3] = bf16_rne(W[j].w);
        *(u16x4*)&Bb[n * kLDK + k4 * 4] = o;
      }
    }
    if (s + 1 < kSLABS) {
      const int real4 = (s + 1 == kSLABS - 1) ? 12 : 48;
#pragma unroll
      for (int j = 0; j < 6; ++j) {
        int q = tid + kTHREADS * j;
        int n = q / 48, k4 = q - n * 48;
        if (q < kNH * 48 && k4 < real4) {
          W[j] = *(const float4*)(wfc + (size_t)(i * kN + nbase + n) * kFTOT +
                                  (size_t)(s + 1) * 192 + k4 * 4);
        } else {
          W[j] = make_float4(0.f, 0.f, 0.f, 0.f);
        }
      }
    }
    __syncthreads();
    {
      const unsigned short* Ar0 = &Ab[(mp * 32 + lc) * kLDK];
      const unsigned short* Ar1 = Ar0 + 16 * kLDK;
      const unsigned short* Br = &Bb[(nt * 16 + lc) * kLDK];
      const int kq = lq * 8;
      const int kmax = (s != kSLABS - 1) ? 6 : 2;
      for (int ks = 0; ks < kmax; ++ks) {
        int ko = ks * 32 + kq;
        bf16x8 a0 = *(const bf16x8*)(Ar0 + ko);
        bf16x8 a1 = *(const bf16x8*)(Ar1 + ko);
        bf16x8 bfr = *(const bf16x8*)(Br + ko);
        acc0 = __builtin_amdgcn_mfma_f32_16x16x32_bf16(a0, bfr, acc0, 0, 0, 0);
        acc1 = __builtin_amdgcn_mfma_f32_16x16x32_bf16(a1, bfr, acc1, 0, 0, 0);
      }
    }
    __syncthreads();
    if (s < kSLABS - 1) {
#pragma unroll
      for (int c = 0; c < 10; ++c) { c1[0][c] = c1[4][c]; c1[1][c] = c1[5][c]; }
    }
  }
  const int nl = nt * 16 + lc;
  if (nl < kNH) {
    const int ng = nbase + nl;
    const float bias = bfc[i * kN + ng];
#pragma unroll
    for (int r = 0; r < 4; ++r) {
      int b0 = mp * 32 + lq * 4 + r;
      float v0 = acc0[r] + bias;
      out[(size_t)(b0 * kI + i) * kN + ng] = 1.0f / (1.0f + __expf(-v0));
      float v1 = acc1[r] + bias;
      out[(size_t)((b0 + 16) * kI + i) * kN + ng] = 1.0f / (1.0f + __expf(-v1));
    }
  }
}

extern "C" void kernel_launch(void* const* d_in, const int* in_sizes, int n_in,
                              void* d_out, int out_size, void* d_ws, size_t ws_size,
                              hipStream_t stream) {
  const float* data = (const float*)d_in[0];
  const float* w1 = (const float*)d_in[1];
  const float* b1 = (const float*)d_in[2];
  const float* w2 = (const float*)d_in[3];
  const float* b2 = (const float*)d_in[4];
  const float* wfc = (const float*)d_in[5];
  const float* bfc = (const float*)d_in[6];
  float* out = (float*)d_out;
  const size_t need = (size_t)kB * kI * kFTOT * 2;  // x bf16: ~148 MB
  if (ws_size >= need) {
    unsigned short* x = (unsigned short*)d_ws;
    conv_kernel<<<dim3(kI * 4), dim3(kTHREADS), 0, stream>>>(data, w1, b1, w2, b2, x);
    gemm_kernel<<<dim3(kI * 2), dim3(kTHREADS), 0, stream>>>(x, wfc, bfc, out);
  } else {
    fused_conv_fc_kernel<<<dim3(kI * 2), dim3(kTHREADS), 0, stream>>>(
        data, w1, b1, w2, b2, wfc, bfc, out);
  }
}